// Round 1
// baseline (230.983 us; speedup 1.0000x reference)
//
#include <hip/hip_runtime.h>
#include <math.h>

#define EPS 1e-10f
#define COS_EPS 1e-8f

// Shapes: img (256,4,3,112,112) fp32; feat (256,4,512); feat_norm (256,4,1)
// Per frame: 3*112*112 = 37632 floats = 9408 float4.
#define NB 256
#define NF 4
#define FRAME_F4 9408     // float4 per frame
#define BLK_PER_B 37      // 37*256 = 9472 >= 9408

// Workspace layout (floats):
// [0,768)     ws_sq[b*3+p]   squared-diff sums
// [768,1536)  ws_neq[b*3+p]  (int) any-not-equal flags (vs frame 0)
// [1536,2304) ws_term[b*3+p] masked penalty terms

__global__ void init_ws(float* ws) {
    int i = blockIdx.x * 256 + threadIdx.x;
    if (i < 1536) ws[i] = 0.0f;   // bit pattern 0 also zeros the int flags
}

__global__ __launch_bounds__(256) void img_reduce(const float* __restrict__ img,
                                                  float* __restrict__ ws_sq,
                                                  int* __restrict__ ws_neq) {
    const int b   = blockIdx.y;
    const int tid = threadIdx.x;
    const int idx = blockIdx.x * 256 + tid;

    float s1 = 0.f, s2 = 0.f, s3 = 0.f;
    int   n1 = 0,   n2 = 0,   n3 = 0;

    if (idx < FRAME_F4) {
        const float4* base = (const float4*)img + (size_t)b * NF * FRAME_F4;
        float4 f0 = base[idx];
        float4 f1 = base[FRAME_F4 + idx];
        float4 f2 = base[2 * FRAME_F4 + idx];
        float4 f3 = base[3 * FRAME_F4 + idx];

        float dx, dy, dz, dw;
        dx = f1.x - f0.x; dy = f1.y - f0.y; dz = f1.z - f0.z; dw = f1.w - f0.w;
        s1 = dx*dx + dy*dy + dz*dz + dw*dw;
        dx = f2.x - f1.x; dy = f2.y - f1.y; dz = f2.z - f1.z; dw = f2.w - f1.w;
        s2 = dx*dx + dy*dy + dz*dz + dw*dw;
        dx = f3.x - f2.x; dy = f3.y - f2.y; dz = f3.z - f2.z; dw = f3.w - f2.w;
        s3 = dx*dx + dy*dy + dz*dz + dw*dw;

        // neq_i: frame i vs frame 0
        n1 = (f1.x != f0.x) | (f1.y != f0.y) | (f1.z != f0.z) | (f1.w != f0.w);
        n2 = (f2.x != f0.x) | (f2.y != f0.y) | (f2.z != f0.z) | (f2.w != f0.w);
        n3 = (f3.x != f0.x) | (f3.y != f0.y) | (f3.z != f0.z) | (f3.w != f0.w);
    }

    // wave(64) reduction
    for (int off = 32; off > 0; off >>= 1) {
        s1 += __shfl_down(s1, off);
        s2 += __shfl_down(s2, off);
        s3 += __shfl_down(s3, off);
        n1 |= __shfl_down(n1, off);
        n2 |= __shfl_down(n2, off);
        n3 |= __shfl_down(n3, off);
    }

    __shared__ float ls[3][4];
    __shared__ int   ln[3][4];
    const int wave = tid >> 6;
    if ((tid & 63) == 0) {
        ls[0][wave] = s1; ls[1][wave] = s2; ls[2][wave] = s3;
        ln[0][wave] = n1; ln[1][wave] = n2; ln[2][wave] = n3;
    }
    __syncthreads();
    if (tid == 0) {
        float t1 = ls[0][0] + ls[0][1] + ls[0][2] + ls[0][3];
        float t2 = ls[1][0] + ls[1][1] + ls[1][2] + ls[1][3];
        float t3 = ls[2][0] + ls[2][1] + ls[2][2] + ls[2][3];
        int   m1 = ln[0][0] | ln[0][1] | ln[0][2] | ln[0][3];
        int   m2 = ln[1][0] | ln[1][1] | ln[1][2] | ln[1][3];
        int   m3 = ln[2][0] | ln[2][1] | ln[2][2] | ln[2][3];
        atomicAdd(&ws_sq[b * 3 + 0], t1);
        atomicAdd(&ws_sq[b * 3 + 1], t2);
        atomicAdd(&ws_sq[b * 3 + 2], t3);
        if (m1) atomicOr(&ws_neq[b * 3 + 0], 1);
        if (m2) atomicOr(&ws_neq[b * 3 + 1], 1);
        if (m3) atomicOr(&ws_neq[b * 3 + 2], 1);
    }
}

// One wave per (b, pair p). 768 waves total = 192 blocks * 4 waves.
__global__ __launch_bounds__(256) void cos_kernel(const float* __restrict__ feat,
                                                  const float* __restrict__ feat_norm,
                                                  const float* __restrict__ ws_sq,
                                                  const int* __restrict__ ws_neq,
                                                  float* __restrict__ ws_term) {
    const int wid  = blockIdx.x * 4 + (threadIdx.x >> 6);   // 0..767
    const int lane = threadIdx.x & 63;
    const int b = wid / 3;
    const int p = wid % 3;

    // feat row = 512 floats = 128 float4
    const float4* fa = (const float4*)feat + ((size_t)b * NF + p) * 128;
    const float4* fb = fa + 128;

    float dab = 0.f, daa = 0.f, dbb = 0.f;
#pragma unroll
    for (int j = 0; j < 2; ++j) {
        float4 a  = fa[lane + 64 * j];
        float4 bb = fb[lane + 64 * j];
        dab += a.x * bb.x + a.y * bb.y + a.z * bb.z + a.w * bb.w;
        daa += a.x * a.x + a.y * a.y + a.z * a.z + a.w * a.w;
        dbb += bb.x * bb.x + bb.y * bb.y + bb.z * bb.z + bb.w * bb.w;
    }
    for (int off = 32; off > 0; off >>= 1) {
        dab += __shfl_down(dab, off);
        daa += __shfl_down(daa, off);
        dbb += __shfl_down(dbb, off);
    }

    if (lane == 0) {
        float na   = fmaxf(sqrtf(daa), COS_EPS);
        float nb   = fmaxf(sqrtf(dbb), COS_EPS);
        float cosv = dab / (na * nb);
        float img_diff = sqrtf(ws_sq[wid]) + EPS;
        float ratio = (1.0f - cosv) / img_diff;      // LIP = 0
        float term  = fmaxf(ratio, 0.0f);            // SQUARED = False
        float fn0   = feat_norm[b * NF];             // feat_norm[b,0,0]
        float w     = 1.0f / (expf(fn0) + EPS);
        bool  cond  = fn0 > 0.0f;                    // fn0 > -TAO, TAO=0
        ws_term[wid] = (cond && ws_neq[wid]) ? term * w : 0.0f;
    }
}

__global__ __launch_bounds__(256) void finalize(const float* __restrict__ feat_norm,
                                                const float* __restrict__ ws_term,
                                                float* __restrict__ out) {
    const int b = threadIdx.x;   // 256 threads, one per batch
    float fn0 = feat_norm[b * NF];
    float w   = 1.0f / (expf(fn0) + EPS);
    bool cond = fn0 > 0.0f;
    out[1 + b] = cond ? w : 0.0f;

    float pen = ws_term[b * 3] + ws_term[b * 3 + 1] + ws_term[b * 3 + 2];
    for (int off = 32; off > 0; off >>= 1) pen += __shfl_down(pen, off);

    __shared__ float sh[4];
    if ((threadIdx.x & 63) == 0) sh[threadIdx.x >> 6] = pen;
    __syncthreads();
    if (threadIdx.x == 0)
        out[0] = (sh[0] + sh[1] + sh[2] + sh[3]) * (1.0f / 256.0f);  // LAMB_LIP=1, mean
}

extern "C" void kernel_launch(void* const* d_in, const int* in_sizes, int n_in,
                              void* d_out, int out_size, void* d_ws, size_t ws_size,
                              hipStream_t stream) {
    const float* img       = (const float*)d_in[0];
    const float* feat      = (const float*)d_in[1];
    const float* feat_norm = (const float*)d_in[2];
    float* out = (float*)d_out;

    float* ws      = (float*)d_ws;
    float* ws_sq   = ws;                  // 768 floats
    int*   ws_neq  = (int*)(ws + 768);    // 768 ints
    float* ws_term = ws + 1536;           // 768 floats

    init_ws<<<6, 256, 0, stream>>>(ws);
    img_reduce<<<dim3(BLK_PER_B, NB), 256, 0, stream>>>(img, ws_sq, ws_neq);
    cos_kernel<<<192, 256, 0, stream>>>(feat, feat_norm, ws_sq, ws_neq, ws_term);
    finalize<<<1, 256, 0, stream>>>(feat_norm, ws_term, out);
}

// Round 2
// 223.619 us; speedup vs baseline: 1.0329x; 1.0329x over previous
//
#include <hip/hip_runtime.h>
#include <math.h>

#define EPS 1e-10f
#define COS_EPS 1e-8f

// Shapes: img (256,4,3,112,112) fp32; feat (256,4,512); feat_norm (256,4,1)
// Per frame: 3*112*112 = 37632 floats = 9408 float4.
#define NB 256
#define NF 4
#define FRAME_F4 9408     // float4 per frame
#define BLK_PER_B 37      // 37*256 = 9472 >= 9408
#define PART_STRIDE 64    // padded partials per (b,pair) for easy lane indexing

// Workspace layout:
//   ws_sq_part : float[768 * 64]  squared-diff partial sums, slot (b*3+p)*64 + blk
//   ws_neq_part: int  [768 * 64]  any-neq partial flags (vs frame 0)
// No init needed: every used slot is written exactly once by stage 1; unused
// lanes (37..63) are guarded out in stage 2.

__global__ __launch_bounds__(256) void img_stage(const float* __restrict__ img,
                                                 float* __restrict__ ws_sq_part,
                                                 int* __restrict__ ws_neq_part) {
    const int b   = blockIdx.y;
    const int bx  = blockIdx.x;
    const int tid = threadIdx.x;
    const int idx = bx * 256 + tid;

    float s1 = 0.f, s2 = 0.f, s3 = 0.f;
    int   n1 = 0,   n2 = 0,   n3 = 0;

    if (idx < FRAME_F4) {
        const float4* base = (const float4*)img + (size_t)b * NF * FRAME_F4;
        float4 f0 = base[idx];
        float4 f1 = base[FRAME_F4 + idx];
        float4 f2 = base[2 * FRAME_F4 + idx];
        float4 f3 = base[3 * FRAME_F4 + idx];

        float dx, dy, dz, dw;
        dx = f1.x - f0.x; dy = f1.y - f0.y; dz = f1.z - f0.z; dw = f1.w - f0.w;
        s1 = dx*dx + dy*dy + dz*dz + dw*dw;
        dx = f2.x - f1.x; dy = f2.y - f1.y; dz = f2.z - f1.z; dw = f2.w - f1.w;
        s2 = dx*dx + dy*dy + dz*dz + dw*dw;
        dx = f3.x - f2.x; dy = f3.y - f2.y; dz = f3.z - f2.z; dw = f3.w - f2.w;
        s3 = dx*dx + dy*dy + dz*dz + dw*dw;

        n1 = (f1.x != f0.x) | (f1.y != f0.y) | (f1.z != f0.z) | (f1.w != f0.w);
        n2 = (f2.x != f0.x) | (f2.y != f0.y) | (f2.z != f0.z) | (f2.w != f0.w);
        n3 = (f3.x != f0.x) | (f3.y != f0.y) | (f3.z != f0.z) | (f3.w != f0.w);
    }

    for (int off = 32; off > 0; off >>= 1) {
        s1 += __shfl_down(s1, off);
        s2 += __shfl_down(s2, off);
        s3 += __shfl_down(s3, off);
        n1 |= __shfl_down(n1, off);
        n2 |= __shfl_down(n2, off);
        n3 |= __shfl_down(n3, off);
    }

    __shared__ float ls[3][4];
    __shared__ int   ln[3][4];
    const int wave = tid >> 6;
    if ((tid & 63) == 0) {
        ls[0][wave] = s1; ls[1][wave] = s2; ls[2][wave] = s3;
        ln[0][wave] = n1; ln[1][wave] = n2; ln[2][wave] = n3;
    }
    __syncthreads();
    if (tid == 0) {
        const int base3 = b * 3;
        ws_sq_part[(base3 + 0) * PART_STRIDE + bx] = ls[0][0] + ls[0][1] + ls[0][2] + ls[0][3];
        ws_sq_part[(base3 + 1) * PART_STRIDE + bx] = ls[1][0] + ls[1][1] + ls[1][2] + ls[1][3];
        ws_sq_part[(base3 + 2) * PART_STRIDE + bx] = ls[2][0] + ls[2][1] + ls[2][2] + ls[2][3];
        ws_neq_part[(base3 + 0) * PART_STRIDE + bx] = ln[0][0] | ln[0][1] | ln[0][2] | ln[0][3];
        ws_neq_part[(base3 + 1) * PART_STRIDE + bx] = ln[1][0] | ln[1][1] | ln[1][2] | ln[1][3];
        ws_neq_part[(base3 + 2) * PART_STRIDE + bx] = ln[2][0] | ln[2][1] | ln[2][2] | ln[2][3];
    }
}

// One block per batch, 192 threads = 3 waves; wave p handles pair p.
// Computes cos similarity, reduces img partials, applies mask/weight,
// writes out[1+b] and atomically accumulates the mean into out[0]
// (out[0] zeroed by a hipMemsetAsync before this kernel).
__global__ __launch_bounds__(192) void batch_stage(const float* __restrict__ feat,
                                                   const float* __restrict__ feat_norm,
                                                   const float* __restrict__ ws_sq_part,
                                                   const int* __restrict__ ws_neq_part,
                                                   float* __restrict__ out) {
    const int b    = blockIdx.x;
    const int tid  = threadIdx.x;
    const int p    = tid >> 6;      // 0..2
    const int lane = tid & 63;

    // feat row = 512 floats = 128 float4
    const float4* fa = (const float4*)feat + ((size_t)b * NF + p) * 128;
    const float4* fb = fa + 128;

    float dab = 0.f, daa = 0.f, dbb = 0.f;
#pragma unroll
    for (int j = 0; j < 2; ++j) {
        float4 a  = fa[lane + 64 * j];
        float4 bb = fb[lane + 64 * j];
        dab += a.x * bb.x + a.y * bb.y + a.z * bb.z + a.w * bb.w;
        daa += a.x * a.x + a.y * a.y + a.z * a.z + a.w * a.w;
        dbb += bb.x * bb.x + bb.y * bb.y + bb.z * bb.z + bb.w * bb.w;
    }

    const int slot = (b * 3 + p) * PART_STRIDE + lane;
    float sq = (lane < BLK_PER_B) ? ws_sq_part[slot] : 0.0f;
    int   nq = (lane < BLK_PER_B) ? ws_neq_part[slot] : 0;

    for (int off = 32; off > 0; off >>= 1) {
        dab += __shfl_down(dab, off);
        daa += __shfl_down(daa, off);
        dbb += __shfl_down(dbb, off);
        sq  += __shfl_down(sq, off);
        nq  |= __shfl_down(nq, off);
    }

    __shared__ float sh_term[3];
    if (lane == 0) {
        float na   = fmaxf(sqrtf(daa), COS_EPS);
        float nb   = fmaxf(sqrtf(dbb), COS_EPS);
        float cosv = dab / (na * nb);
        float img_diff = sqrtf(sq) + EPS;
        float ratio = (1.0f - cosv) / img_diff;      // LIP = 0
        float term  = fmaxf(ratio, 0.0f);            // SQUARED = False
        float fn0   = feat_norm[b * NF];             // feat_norm[b,0,0]
        float w     = 1.0f / (expf(fn0) + EPS);
        bool  cond  = fn0 > 0.0f;                    // fn0 > -TAO, TAO = 0
        sh_term[p]  = (cond && nq) ? term * w : 0.0f;
    }
    __syncthreads();
    if (tid == 0) {
        float fn0 = feat_norm[b * NF];
        float w   = 1.0f / (expf(fn0) + EPS);
        out[1 + b] = (fn0 > 0.0f) ? w : 0.0f;
        float pen = sh_term[0] + sh_term[1] + sh_term[2];
        atomicAdd(&out[0], pen * (1.0f / 256.0f));   // LAMB_LIP = 1, mean over batch
    }
}

extern "C" void kernel_launch(void* const* d_in, const int* in_sizes, int n_in,
                              void* d_out, int out_size, void* d_ws, size_t ws_size,
                              hipStream_t stream) {
    const float* img       = (const float*)d_in[0];
    const float* feat      = (const float*)d_in[1];
    const float* feat_norm = (const float*)d_in[2];
    float* out = (float*)d_out;

    float* ws_sq_part = (float*)d_ws;                       // 768*64 floats = 192 KiB
    int*   ws_neq_part = (int*)((char*)d_ws + 768 * PART_STRIDE * sizeof(float));

    hipMemsetAsync(out, 0, sizeof(float), stream);          // zero the loss accumulator
    img_stage<<<dim3(BLK_PER_B, NB), 256, 0, stream>>>(img, ws_sq_part, ws_neq_part);
    batch_stage<<<NB, 192, 0, stream>>>(feat, feat_norm, ws_sq_part, ws_neq_part, out);
}